// Round 14
// baseline (187.871 us; speedup 1.0000x reference)
//
#include <hip/hip_runtime.h>

typedef __bf16 bf16x8 __attribute__((ext_vector_type(8)));
typedef float f32x4 __attribute__((ext_vector_type(4)));
typedef unsigned short us4 __attribute__((ext_vector_type(4)));

constexpr int TT = 2048;   // tokens
constexpr int CC = 2048;   // channels
constexpr int HH = 16;     // heads
constexpr int DD = 128;    // head dim

__device__ __forceinline__ unsigned short f2bf(float f) {
  unsigned u = __builtin_bit_cast(unsigned, f);
  u += 0x7FFFu + ((u >> 16) & 1u);
  return (unsigned short)(u >> 16);
}
__device__ __forceinline__ float bf2f(unsigned short b) {
  unsigned u = ((unsigned)b) << 16;
  return __builtin_bit_cast(float, u);
}

// async global->LDS, 16B per lane. C-style casts lower to addrspacecast.
__device__ __forceinline__ void gld_lds16(const unsigned short* g, unsigned short* l) {
  __builtin_amdgcn_global_load_lds(
      (const __attribute__((address_space(1))) unsigned int*)g,
      (__attribute__((address_space(3))) unsigned int*)l,
      16, 0, 0);
}

// ---------------- fused f32 -> bf16 convert (5 matrices, one launch) ----------------
__global__ __launch_bounds__(256) void k_cvt5(
    const float* __restrict__ s0, const float* __restrict__ s1,
    const float* __restrict__ s2, const float* __restrict__ s3,
    const float* __restrict__ s4,
    unsigned short* __restrict__ d0, unsigned short* __restrict__ d1,
    unsigned short* __restrict__ d2, unsigned short* __restrict__ d3,
    unsigned short* __restrict__ d4) {
  const int m = blockIdx.y;
  const float* src = (m == 0) ? s0 : (m == 1) ? s1 : (m == 2) ? s2 : (m == 3) ? s3 : s4;
  unsigned short* dst = (m == 0) ? d0 : (m == 1) ? d1 : (m == 2) ? d2 : (m == 3) ? d3 : d4;
  int i = blockIdx.x * 256 + threadIdx.x;
  const float4* s = (const float4*)src;
  float4 a = s[2 * i], b = s[2 * i + 1];
  us4 lo = { f2bf(a.x), f2bf(a.y), f2bf(a.z), f2bf(a.w) };
  us4 hi = { f2bf(b.x), f2bf(b.y), f2bf(b.z), f2bf(b.w) };
  us4* d = (us4*)dst;
  d[2 * i] = lo;
  d[2 * i + 1] = hi;
}

#define WAIT_LGKM0                                      \
  asm volatile("s_waitcnt lgkmcnt(0)" ::: "memory");    \
  __builtin_amdgcn_sched_barrier(0);
#define BAR __builtin_amdgcn_s_barrier();

// ---------------- QKV GEMM: 256x192 tile, 3 phases/tile (16 MFMA each) ----------------
__global__ __launch_bounds__(512, 2) void k_gemm192(
    const unsigned short* __restrict__ A, const unsigned short* __restrict__ B,
    unsigned short* __restrict__ qraw,
    float* __restrict__ outk, float* __restrict__ outv,
    unsigned short* __restrict__ vtb) {
  __shared__ alignas(16) unsigned short As[2][256 * 64];
  __shared__ alignas(16) unsigned short Bs[2][192 * 64];
  const int K = CC, NT = K >> 6, NT2 = NT >> 1;
  const int tid = threadIdx.x;
  const int m0 = blockIdx.y * 256, n0 = blockIdx.x * 192;
  const int wid = tid >> 6, lane = tid & 63;
  const int wr = wid >> 2, wc = wid & 3;
  const int lr = lane & 15, lg = lane >> 4;

  auto stA = [&](int buf, int jb, int tile) {
#pragma unroll
    for (int j = jb; j < jb + 2; ++j) {
      const int ch = tid + j * 512;
      const int r = ch >> 3, c8 = ch & 7;
      gld_lds16(A + (size_t)(m0 + r) * K + tile * 64 + ((c8 ^ (r & 7)) * 8),
                &As[buf][ch * 8]);
    }
  };
  auto stB2 = [&](int buf, int tile) {
#pragma unroll
    for (int j = 0; j < 2; ++j) {
      const int ch = tid + j * 512;
      const int r = ch >> 3, c8 = ch & 7;
      gld_lds16(B + (size_t)(n0 + r) * K + tile * 64 + ((c8 ^ (r & 7)) * 8),
                &Bs[buf][ch * 8]);
    }
  };
  auto stB1 = [&](int buf, int tile) {
    const int ch = tid + 1024;
    const int r = ch >> 3, c8 = ch & 7;
    gld_lds16(B + (size_t)(n0 + r) * K + tile * 64 + ((c8 ^ (r & 7)) * 8),
              &Bs[buf][ch * 8]);
  };

  f32x4 acc[8][3] = {};
  bf16x8 alo[4][2], ahi[4][2], b01[2][2], b2v[2];

  auto rdAlo = [&](int d) {
#pragma unroll
    for (int im = 0; im < 4; ++im)
#pragma unroll
      for (int kk = 0; kk < 2; ++kk) {
        const int row = wr * 128 + im * 16 + lr;
        alo[im][kk] = *(const bf16x8*)(&As[d][row * 64 + (((kk * 4 + lg) ^ (row & 7)) * 8)]);
      }
  };
  auto rdAhi = [&](int d) {
#pragma unroll
    for (int im = 0; im < 4; ++im)
#pragma unroll
      for (int kk = 0; kk < 2; ++kk) {
        const int row = wr * 128 + (4 + im) * 16 + lr;
        ahi[im][kk] = *(const bf16x8*)(&As[d][row * 64 + (((kk * 4 + lg) ^ (row & 7)) * 8)]);
      }
  };
  auto rdB01 = [&](int d) {
#pragma unroll
    for (int in = 0; in < 2; ++in)
#pragma unroll
      for (int kk = 0; kk < 2; ++kk) {
        const int row = wc * 48 + in * 16 + lr;
        b01[in][kk] = *(const bf16x8*)(&Bs[d][row * 64 + (((kk * 4 + lg) ^ (row & 7)) * 8)]);
      }
  };
  auto rdB2 = [&](int d) {
#pragma unroll
    for (int kk = 0; kk < 2; ++kk) {
      const int row = wc * 48 + 32 + lr;
      b2v[kk] = *(const bf16x8*)(&Bs[d][row * 64 + (((kk * 4 + lg) ^ (row & 7)) * 8)]);
    }
  };

  auto q_lo01 = [&]() {
    __builtin_amdgcn_s_setprio(1);
#pragma unroll
    for (int im = 0; im < 4; ++im)
#pragma unroll
      for (int in = 0; in < 2; ++in)
#pragma unroll
        for (int kk = 0; kk < 2; ++kk)
          acc[im][in] = __builtin_amdgcn_mfma_f32_16x16x32_bf16(alo[im][kk], b01[in][kk], acc[im][in], 0, 0, 0);
    __builtin_amdgcn_s_setprio(0);
  };
  auto q_mid16 = [&]() {
    __builtin_amdgcn_s_setprio(1);
#pragma unroll
    for (int im = 0; im < 4; ++im)
#pragma unroll
      for (int kk = 0; kk < 2; ++kk)
        acc[im][2] = __builtin_amdgcn_mfma_f32_16x16x32_bf16(alo[im][kk], b2v[kk], acc[im][2], 0, 0, 0);
#pragma unroll
    for (int im = 0; im < 4; ++im)
#pragma unroll
      for (int kk = 0; kk < 2; ++kk)
        acc[4 + im][2] = __builtin_amdgcn_mfma_f32_16x16x32_bf16(ahi[im][kk], b2v[kk], acc[4 + im][2], 0, 0, 0);
    __builtin_amdgcn_s_setprio(0);
  };
  auto q_hi01 = [&]() {
    __builtin_amdgcn_s_setprio(1);
#pragma unroll
    for (int im = 0; im < 4; ++im)
#pragma unroll
      for (int in = 0; in < 2; ++in)
#pragma unroll
        for (int kk = 0; kk < 2; ++kk)
          acc[4 + im][in] = __builtin_amdgcn_mfma_f32_16x16x32_bf16(ahi[im][kk], b01[in][kk], acc[4 + im][in], 0, 0, 0);
    __builtin_amdgcn_s_setprio(0);
  };

  stB2(0, 0); stB1(0, 0); stA(0, 0, 0); stA(0, 2, 0);
  stB2(1, 1); stB1(1, 1);
  asm volatile("s_waitcnt vmcnt(3)" ::: "memory");
  __builtin_amdgcn_sched_barrier(0);
  BAR

  for (int t = 0; t < NT2; ++t) {
    const int t1 = 2 * t + 1, t2 = 2 * t + 2, t3 = 2 * t + 3;
    const bool s2 = t2 < NT;

    rdAlo(0); rdB01(0);
    stA(1, 0, t1);
    BAR WAIT_LGKM0
    q_lo01();
    BAR
    rdB2(0); rdAhi(0);
    stA(1, 2, t1);
    BAR WAIT_LGKM0
    q_mid16();
    BAR
    if (s2) { stB2(0, t2); stB1(0, t2); }
    q_hi01();
    if (s2) { asm volatile("s_waitcnt vmcnt(3)" ::: "memory"); }
    else    { asm volatile("s_waitcnt vmcnt(0)" ::: "memory"); }
    __builtin_amdgcn_sched_barrier(0);
    BAR

    rdAlo(1); rdB01(1);
    if (s2) stA(0, 0, t2);
    BAR WAIT_LGKM0
    q_lo01();
    BAR
    rdB2(1); rdAhi(1);
    if (s2) stA(0, 2, t2);
    BAR WAIT_LGKM0
    q_mid16();
    BAR
    if (s2) { stB2(1, t3); stB1(1, t3); }
    q_hi01();
    if (s2) { asm volatile("s_waitcnt vmcnt(3)" ::: "memory"); }
    else    { asm volatile("s_waitcnt vmcnt(0)" ::: "memory"); }
    __builtin_amdgcn_sched_barrier(0);
    BAR
  }

#pragma unroll
  for (int mf = 0; mf < 8; ++mf) {
    const int row = m0 + wr * 128 + mf * 16 + lg * 4;
#pragma unroll
    for (int nf = 0; nf < 3; ++nf) {
      const int col = n0 + wc * 48 + nf * 16 + lr;
      if (col < 2048) {
#pragma unroll
        for (int r = 0; r < 4; ++r)
          qraw[(size_t)(row + r) * 2048 + col] = f2bf(acc[mf][nf][r]);
      } else if (col < 4096) {
        const int c = col - 2048;
#pragma unroll
        for (int r = 0; r < 4; ++r)
          outk[(size_t)(c >> 7) * (TT * DD) + (size_t)(row + r) * DD + (c & 127)] = acc[mf][nf][r];
      } else {
        const int c = col - 4096;
        const int hh = c >> 7, d2 = c & 127;
        us4 tv;
#pragma unroll
        for (int r = 0; r < 4; ++r) {
          float v = acc[mf][nf][r];
          outv[(size_t)hh * (TT * DD) + (size_t)(row + r) * DD + d2] = v;
          tv[r] = f2bf(v);
        }
        *(us4*)(vtb + (size_t)hh * (size_t)(DD * TT) + (size_t)d2 * TT + row) = tv;
      }
    }
  }
}

// ---------------- out-proj GEMM: 256x256, 3 phases/tile, split-K, bf16 partials ----
__global__ __launch_bounds__(512, 2) void k_gemm8p(
    const unsigned short* __restrict__ A, const unsigned short* __restrict__ B,
    int N, int K, int kspan,
    unsigned short* __restrict__ out0, unsigned short* __restrict__ out1,
    unsigned short* __restrict__ out2, unsigned short* __restrict__ out3) {
  __shared__ alignas(16) unsigned short As[2][2][128 * 64];
  __shared__ alignas(16) unsigned short Bs[2][2][128 * 64];
  const int tid = threadIdx.x;
  const int m0 = blockIdx.y * 256, n0 = blockIdx.x * 256;
  const int kbeg = blockIdx.z * kspan;
  const int NT = kspan >> 6, NT2 = NT >> 1;
  const int wid = tid >> 6, lane = tid & 63;
  const int wr = wid >> 2, wc = wid & 3;
  const int lr = lane & 15, lg = lane >> 4;
  const int bh = wc >> 1, brow0 = (wc & 1) * 64;

  const int sr0 = tid >> 3, sc0 = tid & 7;
  const unsigned short* Ab = A + kbeg;
  const unsigned short* Bb = B + kbeg;

  auto stageA = [&](int buf, int half, int tile) {
    const int koff = tile * 64;
#pragma unroll
    for (int j = 0; j < 2; ++j) {
      const int r = sr0 + j * 64;
      gld_lds16(Ab + (size_t)(m0 + half * 128 + r) * K + koff + ((sc0 ^ (r & 7)) * 8),
                &As[buf][half][(tid + j * 512) * 8]);
    }
  };
  auto stageB = [&](int buf, int half, int tile) {
    const int koff = tile * 64;
#pragma unroll
    for (int j = 0; j < 2; ++j) {
      const int r = sr0 + j * 64;
      gld_lds16(Bb + (size_t)(n0 + half * 128 + r) * K + koff + ((sc0 ^ (r & 7)) * 8),
                &Bs[buf][half][(tid + j * 512) * 8]);
    }
  };

  f32x4 acc[8][4] = {};
  bf16x8 alo[4][2], ahi[4][2], ba[2][2], bb[2][2];

  auto rdAlo = [&](int d) {
#pragma unroll
    for (int im = 0; im < 4; ++im)
#pragma unroll
      for (int kk = 0; kk < 2; ++kk) {
        const int row = im * 16 + lr;
        alo[im][kk] = *(const bf16x8*)(&As[d][wr][row * 64 + (((kk * 4 + lg) ^ (row & 7)) * 8)]);
      }
  };
  auto rdAhi = [&](int d) {
#pragma unroll
    for (int im = 0; im < 4; ++im)
#pragma unroll
      for (int kk = 0; kk < 2; ++kk) {
        const int row = (4 + im) * 16 + lr;
        ahi[im][kk] = *(const bf16x8*)(&As[d][wr][row * 64 + (((kk * 4 + lg) ^ (row & 7)) * 8)]);
      }
  };
  auto rdBa = [&](int d) {
#pragma unroll
    for (int in = 0; in < 2; ++in)
#pragma unroll
      for (int kk = 0; kk < 2; ++kk) {
        const int row = brow0 + in * 16 + lr;
        ba[in][kk] = *(const bf16x8*)(&Bs[d][bh][row * 64 + (((kk * 4 + lg) ^ (row & 7)) * 8)]);
      }
  };
  auto rdBb = [&](int d) {
#pragma unroll
    for (int in = 0; in < 2; ++in)
#pragma unroll
      for (int kk = 0; kk < 2; ++kk) {
        const int row = brow0 + (2 + in) * 16 + lr;
        bb[in][kk] = *(const bf16x8*)(&Bs[d][bh][row * 64 + (((kk * 4 + lg) ^ (row & 7)) * 8)]);
      }
  };

#define MFMA_Q(MB, NB, AF, BF)                                                     \
  _Pragma("unroll") for (int im = 0; im < 4; ++im)                                 \
      _Pragma("unroll") for (int in = 0; in < 2; ++in)                             \
          _Pragma("unroll") for (int kk = 0; kk < 2; ++kk)                         \
              acc[MB + im][NB + in] = __builtin_amdgcn_mfma_f32_16x16x32_bf16(     \
                  AF[im][kk], BF[in][kk], acc[MB + im][NB + in], 0, 0, 0);

  stageB(0, 0, 0); stageB(0, 1, 0); stageA(0, 0, 0); stageA(0, 1, 0);
  if (NT > 1) { stageB(1, 0, 1); stageB(1, 1, 1); }
  asm volatile("s_waitcnt vmcnt(4)" ::: "memory");
  __builtin_amdgcn_sched_barrier(0);
  BAR

  for (int t = 0; t < NT2; ++t) {
    const int t1 = 2 * t + 1, t2 = 2 * t + 2, t3 = 2 * t + 3;
    const bool s2 = t2 < NT, s3 = t3 < NT;

    rdAlo(0); rdBa(0); rdBb(0);
    stageA(1, 0, t1); stageA(1, 1, t1);
    BAR WAIT_LGKM0
    __builtin_amdgcn_s_setprio(1);
    MFMA_Q(0, 0, alo, ba)
    MFMA_Q(0, 2, alo, bb)
    __builtin_amdgcn_s_setprio(0);
    BAR
    rdAhi(0);
    if (s2) stageB(0, 0, t2);
    BAR WAIT_LGKM0
    __builtin_amdgcn_s_setprio(1);
    MFMA_Q(4, 2, ahi, bb)
    __builtin_amdgcn_s_setprio(0);
    BAR
    if (s2) stageB(0, 1, t2);
    __builtin_amdgcn_s_setprio(1);
    MFMA_Q(4, 0, ahi, ba)
    __builtin_amdgcn_s_setprio(0);
    if (s2) { asm volatile("s_waitcnt vmcnt(4)" ::: "memory"); }
    else    { asm volatile("s_waitcnt vmcnt(0)" ::: "memory"); }
    __builtin_amdgcn_sched_barrier(0);
    BAR

    rdAlo(1); rdBa(1); rdBb(1);
    if (s2) { stageA(0, 0, t2); stageA(0, 1, t2); }
    BAR WAIT_LGKM0
    __builtin_amdgcn_s_setprio(1);
    MFMA_Q(0, 0, alo, ba)
    MFMA_Q(0, 2, alo, bb)
    __builtin_amdgcn_s_setprio(0);
    BAR
    rdAhi(1);
    if (s3) stageB(1, 0, t3);
    BAR WAIT_LGKM0
    __builtin_amdgcn_s_setprio(1);
    MFMA_Q(4, 2, ahi, bb)
    __builtin_amdgcn_s_setprio(0);
    BAR
    if (s3) stageB(1, 1, t3);
    __builtin_amdgcn_s_setprio(1);
    MFMA_Q(4, 0, ahi, ba)
    __builtin_amdgcn_s_setprio(0);
    if (s3) { asm volatile("s_waitcnt vmcnt(4)" ::: "memory"); }
    else    { asm volatile("s_waitcnt vmcnt(0)" ::: "memory"); }
    __builtin_amdgcn_sched_barrier(0);
    BAR
  }
#undef MFMA_Q

  int z = blockIdx.z;
  unsigned short* dst = (z == 0) ? out0 : (z == 1) ? out1 : (z == 2) ? out2 : out3;
#pragma unroll
  for (int mf = 0; mf < 8; ++mf) {
    const int row = m0 + wr * 128 + mf * 16 + lg * 4;
#pragma unroll
    for (int nf = 0; nf < 4; ++nf) {
      const int col = n0 + wc * 64 + nf * 16 + lr;
#pragma unroll
      for (int r = 0; r < 4; ++r) {
        dst[(size_t)(row + r) * N + col] = f2bf(acc[mf][nf][r]);
      }
    }
  }
}
#undef WAIT_LGKM0
#undef BAR

// ---------------- RoPE + scale: shared sincos table (16 heads share angles) ----------
__global__ __launch_bounds__(256) void k_rope(
    const unsigned short* __restrict__ qraw, const float* __restrict__ Kraw,
    const float* __restrict__ sqk,
    unsigned short* __restrict__ qb, unsigned short* __restrict__ kb) {
  const int t = blockIdx.x;
  __shared__ float sn_s[64], cs_s[64];
  if (threadIdx.x < 64) {
    float theta = expf(-(float)threadIdx.x * 0.14391156831212787f);
    float sn, cs;
    sincosf((float)t * theta, &sn, &cs);
    sn_s[threadIdx.x] = sn;
    cs_s[threadIdx.x] = cs;
  }
  __syncthreads();
  for (int i = threadIdx.x; i < HH * 64; i += 256) {
    int h = i >> 6, dp = i & 63;
    float sn = sn_s[dp], cs = cs_s[dp];
    float qr = bf2f(qraw[(size_t)t * CC + h * DD + dp]);
    float qi = bf2f(qraw[(size_t)t * CC + h * DD + dp + 64]);
    const float* kp = Kraw + (size_t)h * TT * DD + (size_t)t * DD;
    float kr = kp[dp], ki = kp[dp + 64];
    float sr = sqk[h * DD + dp];
    float si = sqk[h * DD + dp + 64];
    float qsr = sr * 512.0f, qsi = si * 512.0f;                         // sqrt(C)*sqrt(D)
    float ksr = sr * 45.25483399593904f, ksi = si * 45.25483399593904f; // sqrt(C)
    unsigned short* qo = qb + ((size_t)h * TT + t) * DD;
    unsigned short* ko = kb + ((size_t)h * TT + t) * DD;
    qo[dp]      = f2bf((qr * cs - qi * sn) * qsr);
    qo[dp + 64] = f2bf((qr * sn + qi * cs) * qsi);
    ko[dp]      = f2bf((kr * cs - ki * sn) * ksr);
    ko[dp + 64] = f2bf((kr * sn + ki * cs) * ksi);
  }
}

// ---------------- causal flash attention: mirrored-pair blocks, 3-buf counted KV ----
// grid (16 pairs, 16 heads) = 256 uniform blocks. Waves 0-3 own q-tile gA, 4-7 own
// mirror gB=31-gA (uniform 33 tile-units of MFMA work/block). KV tiles (64 keys)
// cycle through 3 LDS buffers; stage kt+2 during tile kt; end-of-tile vmcnt(4)
// forces kt+1 resident, leaves kt+2's 4 loads in flight (~2 tiles of cover).
// ntiles = gB+1 >= 17 always. Output normalized in-kernel.
__global__ __launch_bounds__(512) void k_attn_pair(
    const unsigned short* __restrict__ qb, const unsigned short* __restrict__ kb,
    const unsigned short* __restrict__ vt, unsigned short* __restrict__ ob) {
  const int gA = blockIdx.x, h = blockIdx.y;
  const int gB = 31 - gA;
  const int ntiles = gB + 1;
  const int tid = threadIdx.x;
  const int wid = tid >> 6, lane = tid & 63;
  const int lr = lane & 15, lg = lane >> 4;
  const int gq = (wid >> 2) ? gB : gA;
  const int q0 = gq * 64 + (wid & 3) * 16;

  __shared__ alignas(16) unsigned short Ks[3][64 * 128];
  __shared__ alignas(16) unsigned short Vs[3][128 * 64];
  __shared__ alignas(16) unsigned short P[8][16][72];

  const unsigned short* qh = qb + (size_t)h * TT * DD;
  const unsigned short* kh = kb + (size_t)h * TT * DD;
  const unsigned short* vh = vt + (size_t)h * DD * TT;

  auto stageKV = [&](int buf, int kt) {  // 4 loads/thread: K0,K1,V0,V1
    const int k0 = kt * 64;
#pragma unroll
    for (int half = 0; half < 2; ++half) {
      int ch = tid + half * 512;
      int r = ch >> 4, c4 = ch & 15;
      gld_lds16(kh + (size_t)(k0 + r) * DD + ((c4 ^ (r & 7)) * 8), Ks[buf] + ch * 8);
    }
#pragma unroll
    for (int half = 0; half < 2; ++half) {
      int ch = tid + half * 512;
      int d = ch >> 3, c8 = ch & 7;
      gld_lds16(vh + (size_t)d * TT + k0 + ((c8 ^ (d & 7)) * 8), Vs[buf] + ch * 8);
    }
  };

  bf16x8 qf[4];
#pragma unroll
  for (int c = 0; c < 4; ++c)
    qf[c] = *(const bf16x8*)(qh + (size_t)(q0 + lr) * DD + c * 32 + lg * 8);

  f32x4 acc[8] = {};
  float mrow[4] = {-3e38f, -3e38f, -3e38f, -3e38f};
  float lsum[4] = {0.f, 0.f, 0.f, 0.f};

  // prologue: stage t0,t1; force t0 (leave t1's 4 loads in flight)
  stageKV(0, 0);
  stageKV(1, 1);  // ntiles >= 17 always
  asm volatile("s_waitcnt vmcnt(4)" ::: "memory");
  __builtin_amdgcn_sched_barrier(0);
  __builtin_amdgcn_s_barrier();

  int cur = 0;
  for (int kt = 0; kt < ntiles; ++kt) {
    const int k0 = kt * 64;
    const bool pf = (kt + 2) < ntiles;
    // stage kt+2 into buffer (cur+2)%3 — its last readers finished at end of kt-1
    if (pf) stageKV((cur + 2) % 3, kt + 2);

    if (k0 <= q0 + 15) {
      f32x4 sv[4] = {};
#pragma unroll
      for (int ktile = 0; ktile < 4; ++ktile) {
        const int row = ktile * 16 + lr;
#pragma unroll
        for (int c = 0; c < 4; ++c) {
          int chn = (c * 4 + lg) ^ (lr & 7);
          bf16x8 kf = *(const bf16x8*)(Ks[cur] + row * 128 + chn * 8);
          sv[ktile] = __builtin_amdgcn_mfma_f32_16x16x32_bf16(qf[c], kf, sv[ktile], 0, 0, 0);
        }
      }
      if (k0 + 63 > q0) {
#pragma unroll
        for (int ktile = 0; ktile < 4; ++ktile)
#pragma unroll
          for (int r = 0; r < 4; ++r) {
            int key = k0 + ktile * 16 + lr;
            int qrow = q0 + lg * 4 + r;
            if (key > qrow) sv[ktile][r] = -1e30f;
          }
      }
      float pmax[4];
#pragma unroll
      for (int r = 0; r < 4; ++r)
        pmax[r] = fmaxf(fmaxf(sv[0][r], sv[1][r]), fmaxf(sv[2][r], sv[3][r]));
#pragma unroll
      for (int msk = 1; msk <= 8; msk <<= 1)
#pragma unroll
        for (int r = 0; r < 4; ++r) pmax[r] = fmaxf(pmax[r], __shfl_xor(pmax[r], msk));
      float p[4][4], ps[4], scl[4];
#pragma unroll
      for (int r = 0; r < 4; ++r) {
        float mn = fmaxf(mrow[r], pmax[r]);
        scl[r] = __expf(mrow[r] - mn);
        mrow[r] = mn;
        ps[r] = 0.f;
#pragma unroll
        for (int ktile = 0; ktile < 4; ++ktile) {
          p[ktile][r] = __expf(sv[ktile][r] - mn);
          ps[r] += p[ktile][r];
        }
      }
#pragma unroll
      for (int msk = 1; msk <= 8; msk <<= 1)
#pragma unroll
        for (int r = 0; r < 4; ++r) ps[r] += __shfl_xor(ps[r], msk);
#pragma unroll
      for (int r = 0; r < 4; ++r) lsum[r] = lsum[r] * scl[r] + ps[r];
#pragma unroll
      for (int n = 0; n < 8; ++n)
#pragma unroll
        for (int r = 0; r < 4; ++r) acc[n][r] *= scl[r];
#pragma unroll
      for (int ktile = 0; ktile < 4; ++ktile)
#pragma unroll
        for (int r = 0; r < 4; ++r)
          P[wid][lg * 4 + r][ktile * 16 + lr] = f2bf(p[ktile][r]);
      asm volatile("s_waitcnt lgkmcnt(0)" ::: "memory");
      __builtin_amdgcn_sched_barrier(0);
      bf16x8 pf2[2];
#pragma unroll
      for (int ks = 0; ks < 2; ++ks)
        pf2[ks] = *(const bf16x8*)(&P[wid][lr][ks * 32 + lg * 8]);
#pragma unroll
      for (int n = 0; n < 8; ++n) {
        const int row = n * 16 + lr;
#pragma unroll
        for (int ks = 0; ks < 2; ++ks) {
          int chn = (ks * 4 + lg) ^ (lr & 7);
          bf16x8 vf = *(const bf16x8*)(Vs[cur] + row * 64 + chn * 8);
          acc[n] = __builtin_amdgcn_mfma_f32_16x16x32_bf16(pf2[ks], vf, acc[n], 0, 0, 0);
        }
      }
    }
    // force kt+1 resident (leave kt+2's 4 loads in flight)
    if (pf) { asm volatile("s_waitcnt vmcnt(4)" ::: "memory"); }
    else    { asm volatile("s_waitcnt vmcnt(0)" ::: "memory"); }
    __builtin_amdgcn_sched_barrier(0);
    __builtin_amdgcn_s_barrier();
    cur = (cur + 1) % 3;
  }

  float inv[4];
#pragma unroll
  for (int r = 0; r < 4; ++r) inv[r] = 1.0f / lsum[r];
#pragma unroll
  for (int n = 0; n < 8; ++n)
#pragma unroll
    for (int r = 0; r < 4; ++r) {
      int t = q0 + lg * 4 + r;
      ob[(size_t)t * CC + h * DD + n * 16 + lr] = f2bf(acc[n][r] * inv[r]);
    }
}

// ---------------- row l2norm over sum of four bf16 split-K partials ----------------
__global__ __launch_bounds__(256) void k_l2norm(
    const unsigned short* __restrict__ Of0, const unsigned short* __restrict__ Of1,
    const unsigned short* __restrict__ Of2, const unsigned short* __restrict__ Of3,
    float* __restrict__ out) {
  const int t = blockIdx.x;
  const int tid = threadIdx.x;
  const size_t base = (size_t)t * CC + tid * 8;
  bf16x8 a0 = *(const bf16x8*)(Of0 + base);
  bf16x8 a1 = *(const bf16x8*)(Of1 + base);
  bf16x8 a2 = *(const bf16x8*)(Of2 + base);
  bf16x8 a3 = *(const bf16x8*)(Of3 + base);
  float v[8];
  float ss = 0.f;
#pragma unroll
  for (int j = 0; j < 8; ++j) {
    v[j] = (float)a0[j] + (float)a1[j] + (float)a2[j] + (float)a3[j];
    ss += v[j] * v[j];
  }
#pragma unroll
  for (int msk = 1; msk < 64; msk <<= 1) ss += __shfl_xor(ss, msk);
  __shared__ float red[4];
  if ((tid & 63) == 0) red[tid >> 6] = ss;
  __syncthreads();
  ss = red[0] + red[1] + red[2] + red[3];
  float sc = 1.0f / fmaxf(sqrtf(ss), 1e-12f);
  float4 oa = { v[0] * sc, v[1] * sc, v[2] * sc, v[3] * sc };
  float4 obv = { v[4] * sc, v[5] * sc, v[6] * sc, v[7] * sc };
  float4* o = (float4*)(out + base);
  o[0] = oa;
  o[1] = obv;
}

extern "C" void kernel_launch(void* const* d_in, const int* in_sizes, int n_in,
                              void* d_out, int out_size, void* d_ws, size_t ws_size,
                              hipStream_t stream) {
  const float* x   = (const float*)d_in[0];
  const float* wq  = (const float*)d_in[1];
  const float* wk  = (const float*)d_in[2];
  const float* wv  = (const float*)d_in[3];
  const float* wo  = (const float*)d_in[4];
  const float* sqk = (const float*)d_in[5];

  float* out_norm = (float*)d_out;
  float* out_k = out_norm + (size_t)4 * 1024 * 1024;
  float* out_v = out_norm + (size_t)8 * 1024 * 1024;

  char* ws = (char*)d_ws;
  unsigned short* xb  = (unsigned short*)(ws);                      // 0..8MB  (dead after QKV)
  unsigned short* w1b = (unsigned short*)(ws + (8u << 20));         // 8..32MB (dead after QKV)
  unsigned short* wob = (unsigned short*)(ws + (32u << 20));        // 32..40MB
  unsigned short* qb  = (unsigned short*)(ws + (40u << 20));        // 40..48MB (dead after attn)
  unsigned short* kb  = (unsigned short*)(ws + (48u << 20));        // 48..56MB (dead after attn)
  unsigned short* vtb = (unsigned short*)(ws + (56u << 20));        // 56..64MB (dead after attn)
  unsigned short* obb = (unsigned short*)(ws + (64u << 20));        // 64..72MB
  unsigned short* qraw = (unsigned short*)(ws + (72u << 20));       // 72..80MB (dead after rope)

  // out-proj split-K=4 bf16 partials (xb/w1b/qb/qraw dead during out-proj)
  unsigned short* Of0 = (unsigned short*)(ws + (72u << 20));  // 72..80MB
  unsigned short* Of1 = (unsigned short*)(ws);                // 0..8MB
  unsigned short* Of2 = (unsigned short*)(ws + (8u << 20));   // 8..16MB
  unsigned short* Of3 = (unsigned short*)(ws + (16u << 20));  // 16..24MB

  // fused converts: one launch, 5 matrices
  k_cvt5<<<dim3(2048, 5), 256, 0, stream>>>(
      x, wq, wk, wv, wo,
      xb, w1b, w1b + (size_t)4 * 1024 * 1024, w1b + (size_t)8 * 1024 * 1024, wob);

  // fused QKV projection (+ fused V-transpose): 2048 x 6144 x 2048, 256 blocks
  k_gemm192<<<dim3(32, 8), 512, 0, stream>>>(xb, w1b, qraw, out_k, out_v, vtb);

  k_rope<<<TT, 256, 0, stream>>>(qraw, out_k, sqk, qb, kb);

  // attention: mirrored-pair blocks, 3-buffer counted-vmcnt KV pipeline
  k_attn_pair<<<dim3(16, 16), 512, 0, stream>>>(qb, kb, vtb, obb);

  // output projection: 2048 x 2048 x 2048, split-K=4 (256 blocks), bf16 partials
  k_gemm8p<<<dim3(8, 8, 4), 512, 0, stream>>>(obb, wob, CC, CC, CC / 4,
                                              Of0, Of1, Of2, Of3);

  k_l2norm<<<TT, 256, 0, stream>>>(Of0, Of1, Of2, Of3, out_norm);
}

// Round 15
// 182.571 us; speedup vs baseline: 1.0290x; 1.0290x over previous
//
#include <hip/hip_runtime.h>

typedef __bf16 bf16x8 __attribute__((ext_vector_type(8)));
typedef float f32x4 __attribute__((ext_vector_type(4)));
typedef unsigned short us4 __attribute__((ext_vector_type(4)));

constexpr int TT = 2048;   // tokens
constexpr int CC = 2048;   // channels
constexpr int HH = 16;     // heads
constexpr int DD = 128;    // head dim

__device__ __forceinline__ unsigned short f2bf(float f) {
  unsigned u = __builtin_bit_cast(unsigned, f);
  u += 0x7FFFu + ((u >> 16) & 1u);
  return (unsigned short)(u >> 16);
}
__device__ __forceinline__ float bf2f(unsigned short b) {
  unsigned u = ((unsigned)b) << 16;
  return __builtin_bit_cast(float, u);
}

// async global->LDS, 16B per lane. C-style casts lower to addrspacecast.
__device__ __forceinline__ void gld_lds16(const unsigned short* g, unsigned short* l) {
  __builtin_amdgcn_global_load_lds(
      (const __attribute__((address_space(1))) unsigned int*)g,
      (__attribute__((address_space(3))) unsigned int*)l,
      16, 0, 0);
}

// ---------------- fused f32 -> bf16 convert (5 matrices, one launch) ----------------
__global__ __launch_bounds__(256) void k_cvt5(
    const float* __restrict__ s0, const float* __restrict__ s1,
    const float* __restrict__ s2, const float* __restrict__ s3,
    const float* __restrict__ s4,
    unsigned short* __restrict__ d0, unsigned short* __restrict__ d1,
    unsigned short* __restrict__ d2, unsigned short* __restrict__ d3,
    unsigned short* __restrict__ d4) {
  const int m = blockIdx.y;
  const float* src = (m == 0) ? s0 : (m == 1) ? s1 : (m == 2) ? s2 : (m == 3) ? s3 : s4;
  unsigned short* dst = (m == 0) ? d0 : (m == 1) ? d1 : (m == 2) ? d2 : (m == 3) ? d3 : d4;
  int i = blockIdx.x * 256 + threadIdx.x;
  const float4* s = (const float4*)src;
  float4 a = s[2 * i], b = s[2 * i + 1];
  us4 lo = { f2bf(a.x), f2bf(a.y), f2bf(a.z), f2bf(a.w) };
  us4 hi = { f2bf(b.x), f2bf(b.y), f2bf(b.z), f2bf(b.w) };
  us4* d = (us4*)dst;
  d[2 * i] = lo;
  d[2 * i + 1] = hi;
}

#define WAIT_LGKM0                                      \
  asm volatile("s_waitcnt lgkmcnt(0)" ::: "memory");    \
  __builtin_amdgcn_sched_barrier(0);
#define BAR __builtin_amdgcn_s_barrier();

// ---------------- QKV GEMM: 256x192 tile, 3 phases/tile (16 MFMA each) ----------------
__global__ __launch_bounds__(512, 2) void k_gemm192(
    const unsigned short* __restrict__ A, const unsigned short* __restrict__ B,
    unsigned short* __restrict__ qraw,
    float* __restrict__ outk, float* __restrict__ outv,
    unsigned short* __restrict__ vtb) {
  __shared__ alignas(16) unsigned short As[2][256 * 64];
  __shared__ alignas(16) unsigned short Bs[2][192 * 64];
  const int K = CC, NT = K >> 6, NT2 = NT >> 1;
  const int tid = threadIdx.x;
  const int m0 = blockIdx.y * 256, n0 = blockIdx.x * 192;
  const int wid = tid >> 6, lane = tid & 63;
  const int wr = wid >> 2, wc = wid & 3;
  const int lr = lane & 15, lg = lane >> 4;

  auto stA = [&](int buf, int jb, int tile) {
#pragma unroll
    for (int j = jb; j < jb + 2; ++j) {
      const int ch = tid + j * 512;
      const int r = ch >> 3, c8 = ch & 7;
      gld_lds16(A + (size_t)(m0 + r) * K + tile * 64 + ((c8 ^ (r & 7)) * 8),
                &As[buf][ch * 8]);
    }
  };
  auto stB2 = [&](int buf, int tile) {
#pragma unroll
    for (int j = 0; j < 2; ++j) {
      const int ch = tid + j * 512;
      const int r = ch >> 3, c8 = ch & 7;
      gld_lds16(B + (size_t)(n0 + r) * K + tile * 64 + ((c8 ^ (r & 7)) * 8),
                &Bs[buf][ch * 8]);
    }
  };
  auto stB1 = [&](int buf, int tile) {
    const int ch = tid + 1024;
    const int r = ch >> 3, c8 = ch & 7;
    gld_lds16(B + (size_t)(n0 + r) * K + tile * 64 + ((c8 ^ (r & 7)) * 8),
              &Bs[buf][ch * 8]);
  };

  f32x4 acc[8][3] = {};
  bf16x8 alo[4][2], ahi[4][2], b01[2][2], b2v[2];

  auto rdAlo = [&](int d) {
#pragma unroll
    for (int im = 0; im < 4; ++im)
#pragma unroll
      for (int kk = 0; kk < 2; ++kk) {
        const int row = wr * 128 + im * 16 + lr;
        alo[im][kk] = *(const bf16x8*)(&As[d][row * 64 + (((kk * 4 + lg) ^ (row & 7)) * 8)]);
      }
  };
  auto rdAhi = [&](int d) {
#pragma unroll
    for (int im = 0; im < 4; ++im)
#pragma unroll
      for (int kk = 0; kk < 2; ++kk) {
        const int row = wr * 128 + (4 + im) * 16 + lr;
        ahi[im][kk] = *(const bf16x8*)(&As[d][row * 64 + (((kk * 4 + lg) ^ (row & 7)) * 8)]);
      }
  };
  auto rdB01 = [&](int d) {
#pragma unroll
    for (int in = 0; in < 2; ++in)
#pragma unroll
      for (int kk = 0; kk < 2; ++kk) {
        const int row = wc * 48 + in * 16 + lr;
        b01[in][kk] = *(const bf16x8*)(&Bs[d][row * 64 + (((kk * 4 + lg) ^ (row & 7)) * 8)]);
      }
  };
  auto rdB2 = [&](int d) {
#pragma unroll
    for (int kk = 0; kk < 2; ++kk) {
      const int row = wc * 48 + 32 + lr;
      b2v[kk] = *(const bf16x8*)(&Bs[d][row * 64 + (((kk * 4 + lg) ^ (row & 7)) * 8)]);
    }
  };

  auto q_lo01 = [&]() {
    __builtin_amdgcn_s_setprio(1);
#pragma unroll
    for (int im = 0; im < 4; ++im)
#pragma unroll
      for (int in = 0; in < 2; ++in)
#pragma unroll
        for (int kk = 0; kk < 2; ++kk)
          acc[im][in] = __builtin_amdgcn_mfma_f32_16x16x32_bf16(alo[im][kk], b01[in][kk], acc[im][in], 0, 0, 0);
    __builtin_amdgcn_s_setprio(0);
  };
  auto q_mid16 = [&]() {
    __builtin_amdgcn_s_setprio(1);
#pragma unroll
    for (int im = 0; im < 4; ++im)
#pragma unroll
      for (int kk = 0; kk < 2; ++kk)
        acc[im][2] = __builtin_amdgcn_mfma_f32_16x16x32_bf16(alo[im][kk], b2v[kk], acc[im][2], 0, 0, 0);
#pragma unroll
    for (int im = 0; im < 4; ++im)
#pragma unroll
      for (int kk = 0; kk < 2; ++kk)
        acc[4 + im][2] = __builtin_amdgcn_mfma_f32_16x16x32_bf16(ahi[im][kk], b2v[kk], acc[4 + im][2], 0, 0, 0);
    __builtin_amdgcn_s_setprio(0);
  };
  auto q_hi01 = [&]() {
    __builtin_amdgcn_s_setprio(1);
#pragma unroll
    for (int im = 0; im < 4; ++im)
#pragma unroll
      for (int in = 0; in < 2; ++in)
#pragma unroll
        for (int kk = 0; kk < 2; ++kk)
          acc[4 + im][in] = __builtin_amdgcn_mfma_f32_16x16x32_bf16(ahi[im][kk], b01[in][kk], acc[4 + im][in], 0, 0, 0);
    __builtin_amdgcn_s_setprio(0);
  };

  stB2(0, 0); stB1(0, 0); stA(0, 0, 0); stA(0, 2, 0);
  stB2(1, 1); stB1(1, 1);
  asm volatile("s_waitcnt vmcnt(3)" ::: "memory");
  __builtin_amdgcn_sched_barrier(0);
  BAR

  for (int t = 0; t < NT2; ++t) {
    const int t1 = 2 * t + 1, t2 = 2 * t + 2, t3 = 2 * t + 3;
    const bool s2 = t2 < NT;

    rdAlo(0); rdB01(0);
    stA(1, 0, t1);
    BAR WAIT_LGKM0
    q_lo01();
    BAR
    rdB2(0); rdAhi(0);
    stA(1, 2, t1);
    BAR WAIT_LGKM0
    q_mid16();
    BAR
    if (s2) { stB2(0, t2); stB1(0, t2); }
    q_hi01();
    if (s2) { asm volatile("s_waitcnt vmcnt(3)" ::: "memory"); }
    else    { asm volatile("s_waitcnt vmcnt(0)" ::: "memory"); }
    __builtin_amdgcn_sched_barrier(0);
    BAR

    rdAlo(1); rdB01(1);
    if (s2) stA(0, 0, t2);
    BAR WAIT_LGKM0
    q_lo01();
    BAR
    rdB2(1); rdAhi(1);
    if (s2) stA(0, 2, t2);
    BAR WAIT_LGKM0
    q_mid16();
    BAR
    if (s2) { stB2(1, t3); stB1(1, t3); }
    q_hi01();
    if (s2) { asm volatile("s_waitcnt vmcnt(3)" ::: "memory"); }
    else    { asm volatile("s_waitcnt vmcnt(0)" ::: "memory"); }
    __builtin_amdgcn_sched_barrier(0);
    BAR
  }

#pragma unroll
  for (int mf = 0; mf < 8; ++mf) {
    const int row = m0 + wr * 128 + mf * 16 + lg * 4;
#pragma unroll
    for (int nf = 0; nf < 3; ++nf) {
      const int col = n0 + wc * 48 + nf * 16 + lr;
      if (col < 2048) {
#pragma unroll
        for (int r = 0; r < 4; ++r)
          qraw[(size_t)(row + r) * 2048 + col] = f2bf(acc[mf][nf][r]);
      } else if (col < 4096) {
        const int c = col - 2048;
#pragma unroll
        for (int r = 0; r < 4; ++r)
          outk[(size_t)(c >> 7) * (TT * DD) + (size_t)(row + r) * DD + (c & 127)] = acc[mf][nf][r];
      } else {
        const int c = col - 4096;
        const int hh = c >> 7, d2 = c & 127;
        us4 tv;
#pragma unroll
        for (int r = 0; r < 4; ++r) {
          float v = acc[mf][nf][r];
          outv[(size_t)hh * (TT * DD) + (size_t)(row + r) * DD + d2] = v;
          tv[r] = f2bf(v);
        }
        *(us4*)(vtb + (size_t)hh * (size_t)(DD * TT) + (size_t)d2 * TT + row) = tv;
      }
    }
  }
}

// ---------------- out-proj GEMM: 256x256, 3 phases/tile, split-K, bf16 partials ----
__global__ __launch_bounds__(512, 2) void k_gemm8p(
    const unsigned short* __restrict__ A, const unsigned short* __restrict__ B,
    int N, int K, int kspan,
    unsigned short* __restrict__ out0, unsigned short* __restrict__ out1,
    unsigned short* __restrict__ out2, unsigned short* __restrict__ out3) {
  __shared__ alignas(16) unsigned short As[2][2][128 * 64];
  __shared__ alignas(16) unsigned short Bs[2][2][128 * 64];
  const int tid = threadIdx.x;
  const int m0 = blockIdx.y * 256, n0 = blockIdx.x * 256;
  const int kbeg = blockIdx.z * kspan;
  const int NT = kspan >> 6, NT2 = NT >> 1;
  const int wid = tid >> 6, lane = tid & 63;
  const int wr = wid >> 2, wc = wid & 3;
  const int lr = lane & 15, lg = lane >> 4;
  const int bh = wc >> 1, brow0 = (wc & 1) * 64;

  const int sr0 = tid >> 3, sc0 = tid & 7;
  const unsigned short* Ab = A + kbeg;
  const unsigned short* Bb = B + kbeg;

  auto stageA = [&](int buf, int half, int tile) {
    const int koff = tile * 64;
#pragma unroll
    for (int j = 0; j < 2; ++j) {
      const int r = sr0 + j * 64;
      gld_lds16(Ab + (size_t)(m0 + half * 128 + r) * K + koff + ((sc0 ^ (r & 7)) * 8),
                &As[buf][half][(tid + j * 512) * 8]);
    }
  };
  auto stageB = [&](int buf, int half, int tile) {
    const int koff = tile * 64;
#pragma unroll
    for (int j = 0; j < 2; ++j) {
      const int r = sr0 + j * 64;
      gld_lds16(Bb + (size_t)(n0 + half * 128 + r) * K + koff + ((sc0 ^ (r & 7)) * 8),
                &Bs[buf][half][(tid + j * 512) * 8]);
    }
  };

  f32x4 acc[8][4] = {};
  bf16x8 alo[4][2], ahi[4][2], ba[2][2], bb[2][2];

  auto rdAlo = [&](int d) {
#pragma unroll
    for (int im = 0; im < 4; ++im)
#pragma unroll
      for (int kk = 0; kk < 2; ++kk) {
        const int row = im * 16 + lr;
        alo[im][kk] = *(const bf16x8*)(&As[d][wr][row * 64 + (((kk * 4 + lg) ^ (row & 7)) * 8)]);
      }
  };
  auto rdAhi = [&](int d) {
#pragma unroll
    for (int im = 0; im < 4; ++im)
#pragma unroll
      for (int kk = 0; kk < 2; ++kk) {
        const int row = (4 + im) * 16 + lr;
        ahi[im][kk] = *(const bf16x8*)(&As[d][wr][row * 64 + (((kk * 4 + lg) ^ (row & 7)) * 8)]);
      }
  };
  auto rdBa = [&](int d) {
#pragma unroll
    for (int in = 0; in < 2; ++in)
#pragma unroll
      for (int kk = 0; kk < 2; ++kk) {
        const int row = brow0 + in * 16 + lr;
        ba[in][kk] = *(const bf16x8*)(&Bs[d][bh][row * 64 + (((kk * 4 + lg) ^ (row & 7)) * 8)]);
      }
  };
  auto rdBb = [&](int d) {
#pragma unroll
    for (int in = 0; in < 2; ++in)
#pragma unroll
      for (int kk = 0; kk < 2; ++kk) {
        const int row = brow0 + (2 + in) * 16 + lr;
        bb[in][kk] = *(const bf16x8*)(&Bs[d][bh][row * 64 + (((kk * 4 + lg) ^ (row & 7)) * 8)]);
      }
  };

#define MFMA_Q(MB, NB, AF, BF)                                                     \
  _Pragma("unroll") for (int im = 0; im < 4; ++im)                                 \
      _Pragma("unroll") for (int in = 0; in < 2; ++in)                             \
          _Pragma("unroll") for (int kk = 0; kk < 2; ++kk)                         \
              acc[MB + im][NB + in] = __builtin_amdgcn_mfma_f32_16x16x32_bf16(     \
                  AF[im][kk], BF[in][kk], acc[MB + im][NB + in], 0, 0, 0);

  stageB(0, 0, 0); stageB(0, 1, 0); stageA(0, 0, 0); stageA(0, 1, 0);
  if (NT > 1) { stageB(1, 0, 1); stageB(1, 1, 1); }
  asm volatile("s_waitcnt vmcnt(4)" ::: "memory");
  __builtin_amdgcn_sched_barrier(0);
  BAR

  for (int t = 0; t < NT2; ++t) {
    const int t1 = 2 * t + 1, t2 = 2 * t + 2, t3 = 2 * t + 3;
    const bool s2 = t2 < NT, s3 = t3 < NT;

    rdAlo(0); rdBa(0); rdBb(0);
    stageA(1, 0, t1); stageA(1, 1, t1);
    BAR WAIT_LGKM0
    __builtin_amdgcn_s_setprio(1);
    MFMA_Q(0, 0, alo, ba)
    MFMA_Q(0, 2, alo, bb)
    __builtin_amdgcn_s_setprio(0);
    BAR
    rdAhi(0);
    if (s2) stageB(0, 0, t2);
    BAR WAIT_LGKM0
    __builtin_amdgcn_s_setprio(1);
    MFMA_Q(4, 2, ahi, bb)
    __builtin_amdgcn_s_setprio(0);
    BAR
    if (s2) stageB(0, 1, t2);
    __builtin_amdgcn_s_setprio(1);
    MFMA_Q(4, 0, ahi, ba)
    __builtin_amdgcn_s_setprio(0);
    if (s2) { asm volatile("s_waitcnt vmcnt(4)" ::: "memory"); }
    else    { asm volatile("s_waitcnt vmcnt(0)" ::: "memory"); }
    __builtin_amdgcn_sched_barrier(0);
    BAR

    rdAlo(1); rdBa(1); rdBb(1);
    if (s2) { stageA(0, 0, t2); stageA(0, 1, t2); }
    BAR WAIT_LGKM0
    __builtin_amdgcn_s_setprio(1);
    MFMA_Q(0, 0, alo, ba)
    MFMA_Q(0, 2, alo, bb)
    __builtin_amdgcn_s_setprio(0);
    BAR
    rdAhi(1);
    if (s3) stageB(1, 0, t3);
    BAR WAIT_LGKM0
    __builtin_amdgcn_s_setprio(1);
    MFMA_Q(4, 2, ahi, bb)
    __builtin_amdgcn_s_setprio(0);
    BAR
    if (s3) stageB(1, 1, t3);
    __builtin_amdgcn_s_setprio(1);
    MFMA_Q(4, 0, ahi, ba)
    __builtin_amdgcn_s_setprio(0);
    if (s3) { asm volatile("s_waitcnt vmcnt(4)" ::: "memory"); }
    else    { asm volatile("s_waitcnt vmcnt(0)" ::: "memory"); }
    __builtin_amdgcn_sched_barrier(0);
    BAR
  }
#undef MFMA_Q

  int z = blockIdx.z;
  unsigned short* dst = (z == 0) ? out0 : (z == 1) ? out1 : (z == 2) ? out2 : out3;
#pragma unroll
  for (int mf = 0; mf < 8; ++mf) {
    const int row = m0 + wr * 128 + mf * 16 + lg * 4;
#pragma unroll
    for (int nf = 0; nf < 4; ++nf) {
      const int col = n0 + wc * 64 + nf * 16 + lr;
#pragma unroll
      for (int r = 0; r < 4; ++r) {
        dst[(size_t)(row + r) * N + col] = f2bf(acc[mf][nf][r]);
      }
    }
  }
}
#undef WAIT_LGKM0
#undef BAR

// ---------------- RoPE + scale: shared sincos table (16 heads share angles) ----------
__global__ __launch_bounds__(256) void k_rope(
    const unsigned short* __restrict__ qraw, const float* __restrict__ Kraw,
    const float* __restrict__ sqk,
    unsigned short* __restrict__ qb, unsigned short* __restrict__ kb) {
  const int t = blockIdx.x;
  __shared__ float sn_s[64], cs_s[64];
  if (threadIdx.x < 64) {
    float theta = expf(-(float)threadIdx.x * 0.14391156831212787f);
    float sn, cs;
    sincosf((float)t * theta, &sn, &cs);
    sn_s[threadIdx.x] = sn;
    cs_s[threadIdx.x] = cs;
  }
  __syncthreads();
  for (int i = threadIdx.x; i < HH * 64; i += 256) {
    int h = i >> 6, dp = i & 63;
    float sn = sn_s[dp], cs = cs_s[dp];
    float qr = bf2f(qraw[(size_t)t * CC + h * DD + dp]);
    float qi = bf2f(qraw[(size_t)t * CC + h * DD + dp + 64]);
    const float* kp = Kraw + (size_t)h * TT * DD + (size_t)t * DD;
    float kr = kp[dp], ki = kp[dp + 64];
    float sr = sqk[h * DD + dp];
    float si = sqk[h * DD + dp + 64];
    float qsr = sr * 512.0f, qsi = si * 512.0f;                         // sqrt(C)*sqrt(D)
    float ksr = sr * 45.25483399593904f, ksi = si * 45.25483399593904f; // sqrt(C)
    unsigned short* qo = qb + ((size_t)h * TT + t) * DD;
    unsigned short* ko = kb + ((size_t)h * TT + t) * DD;
    qo[dp]      = f2bf((qr * cs - qi * sn) * qsr);
    qo[dp + 64] = f2bf((qr * sn + qi * cs) * qsi);
    ko[dp]      = f2bf((kr * cs - ki * sn) * ksr);
    ko[dp + 64] = f2bf((kr * sn + ki * cs) * ksi);
  }
}

// ---------------- causal flash attention: 4-wave blocks, 2 blocks/CU ----------------
// grid (x=16 heads, y=32): gA = gy<16 ? gy : 47-gy. Linear dispatch pairs CU c with
// blocks {gA=c/16, gA=31-c/16} -> uniform 33 tile-units/CU. Block = 4 waves, one
// 64-row q-tile, ntiles = gA+1 (NO idle waves). LDS 73KB -> 2 independent
// blocks/CU overlap each other's serial chains. KV dbuf: stage t+1 during t.
__global__ __launch_bounds__(256, 2) void k_attn(
    const unsigned short* __restrict__ qb, const unsigned short* __restrict__ kb,
    const unsigned short* __restrict__ vt, unsigned short* __restrict__ ob) {
  const int h = blockIdx.x;
  const int gy = blockIdx.y;
  const int gA = (gy < 16) ? gy : 47 - gy;
  const int ntiles = gA + 1;
  const int tid = threadIdx.x;
  const int wid = tid >> 6, lane = tid & 63;
  const int lr = lane & 15, lg = lane >> 4;
  const int q0 = gA * 64 + wid * 16;

  __shared__ alignas(16) unsigned short Ks[2][64 * 128];
  __shared__ alignas(16) unsigned short Vs[2][128 * 64];
  __shared__ alignas(16) unsigned short P[4][16][72];

  const unsigned short* qh = qb + (size_t)h * TT * DD;
  const unsigned short* kh = kb + (size_t)h * TT * DD;
  const unsigned short* vh = vt + (size_t)h * DD * TT;

  auto stageKV = [&](int buf, int kt) {  // 256 threads x 8 chunks of 16B
    const int k0 = kt * 64;
#pragma unroll
    for (int j = 0; j < 4; ++j) {
      int ch = tid + j * 256;
      int r = ch >> 4, c4 = ch & 15;
      gld_lds16(kh + (size_t)(k0 + r) * DD + ((c4 ^ (r & 7)) * 8), Ks[buf] + ch * 8);
    }
#pragma unroll
    for (int j = 0; j < 4; ++j) {
      int ch = tid + j * 256;
      int d = ch >> 3, c8 = ch & 7;
      gld_lds16(vh + (size_t)d * TT + k0 + ((c8 ^ (d & 7)) * 8), Vs[buf] + ch * 8);
    }
  };

  bf16x8 qf[4];
#pragma unroll
  for (int c = 0; c < 4; ++c)
    qf[c] = *(const bf16x8*)(qh + (size_t)(q0 + lr) * DD + c * 32 + lg * 8);

  f32x4 acc[8] = {};
  float mrow[4] = {-3e38f, -3e38f, -3e38f, -3e38f};
  float lsum[4] = {0.f, 0.f, 0.f, 0.f};

  stageKV(0, 0);
  asm volatile("s_waitcnt vmcnt(0)" ::: "memory");
  __builtin_amdgcn_sched_barrier(0);
  __builtin_amdgcn_s_barrier();

  for (int kt = 0; kt < ntiles; ++kt) {
    const int cur = kt & 1;
    const int k0 = kt * 64;
    const bool pf = (kt + 1) < ntiles;
    if (pf) stageKV(cur ^ 1, kt + 1);

    {
      f32x4 sv[4] = {};
#pragma unroll
      for (int ktile = 0; ktile < 4; ++ktile) {
        const int row = ktile * 16 + lr;
#pragma unroll
        for (int c = 0; c < 4; ++c) {
          int chn = (c * 4 + lg) ^ (lr & 7);
          bf16x8 kf = *(const bf16x8*)(Ks[cur] + row * 128 + chn * 8);
          sv[ktile] = __builtin_amdgcn_mfma_f32_16x16x32_bf16(qf[c], kf, sv[ktile], 0, 0, 0);
        }
      }
      if (k0 + 63 > q0) {  // diagonal tile: causal mask
#pragma unroll
        for (int ktile = 0; ktile < 4; ++ktile)
#pragma unroll
          for (int r = 0; r < 4; ++r) {
            int key = k0 + ktile * 16 + lr;
            int qrow = q0 + lg * 4 + r;
            if (key > qrow) sv[ktile][r] = -1e30f;
          }
      }
      float pmax[4];
#pragma unroll
      for (int r = 0; r < 4; ++r)
        pmax[r] = fmaxf(fmaxf(sv[0][r], sv[1][r]), fmaxf(sv[2][r], sv[3][r]));
#pragma unroll
      for (int msk = 1; msk <= 8; msk <<= 1)
#pragma unroll
        for (int r = 0; r < 4; ++r) pmax[r] = fmaxf(pmax[r], __shfl_xor(pmax[r], msk));
      float p[4][4], ps[4], scl[4];
#pragma unroll
      for (int r = 0; r < 4; ++r) {
        float mn = fmaxf(mrow[r], pmax[r]);
        scl[r] = __expf(mrow[r] - mn);
        mrow[r] = mn;
        ps[r] = 0.f;
#pragma unroll
        for (int ktile = 0; ktile < 4; ++ktile) {
          p[ktile][r] = __expf(sv[ktile][r] - mn);
          ps[r] += p[ktile][r];
        }
      }
#pragma unroll
      for (int msk = 1; msk <= 8; msk <<= 1)
#pragma unroll
        for (int r = 0; r < 4; ++r) ps[r] += __shfl_xor(ps[r], msk);
#pragma unroll
      for (int r = 0; r < 4; ++r) lsum[r] = lsum[r] * scl[r] + ps[r];
#pragma unroll
      for (int n = 0; n < 8; ++n)
#pragma unroll
        for (int r = 0; r < 4; ++r) acc[n][r] *= scl[r];
#pragma unroll
      for (int ktile = 0; ktile < 4; ++ktile)
#pragma unroll
        for (int r = 0; r < 4; ++r)
          P[wid][lg * 4 + r][ktile * 16 + lr] = f2bf(p[ktile][r]);
      asm volatile("s_waitcnt lgkmcnt(0)" ::: "memory");
      __builtin_amdgcn_sched_barrier(0);
      bf16x8 pf2[2];
#pragma unroll
      for (int ks = 0; ks < 2; ++ks)
        pf2[ks] = *(const bf16x8*)(&P[wid][lr][ks * 32 + lg * 8]);
#pragma unroll
      for (int n = 0; n < 8; ++n) {
        const int row = n * 16 + lr;
#pragma unroll
        for (int ks = 0; ks < 2; ++ks) {
          int chn = (ks * 4 + lg) ^ (lr & 7);
          bf16x8 vf = *(const bf16x8*)(Vs[cur] + row * 64 + chn * 8);
          acc[n] = __builtin_amdgcn_mfma_f32_16x16x32_bf16(pf2[ks], vf, acc[n], 0, 0, 0);
        }
      }
    }
    if (pf) {
      asm volatile("s_waitcnt vmcnt(0)" ::: "memory");
      __builtin_amdgcn_sched_barrier(0);
      __builtin_amdgcn_s_barrier();
    }
  }

  float inv[4];
#pragma unroll
  for (int r = 0; r < 4; ++r) inv[r] = 1.0f / lsum[r];
#pragma unroll
  for (int n = 0; n < 8; ++n)
#pragma unroll
    for (int r = 0; r < 4; ++r) {
      int t = q0 + lg * 4 + r;
      ob[(size_t)t * CC + h * DD + n * 16 + lr] = f2bf(acc[n][r] * inv[r]);
    }
}

// ---------------- row l2norm over sum of four bf16 split-K partials ----------------
__global__ __launch_bounds__(256) void k_l2norm(
    const unsigned short* __restrict__ Of0, const unsigned short* __restrict__ Of1,
    const unsigned short* __restrict__ Of2, const unsigned short* __restrict__ Of3,
    float* __restrict__ out) {
  const int t = blockIdx.x;
  const int tid = threadIdx.x;
  const size_t base = (size_t)t * CC + tid * 8;
  bf16x8 a0 = *(const bf16x8*)(Of0 + base);
  bf16x8 a1 = *(const bf16x8*)(Of1 + base);
  bf16x8 a2 = *(const bf16x8*)(Of2 + base);
  bf16x8 a3 = *(const bf16x8*)(Of3 + base);
  float v[8];
  float ss = 0.f;
#pragma unroll
  for (int j = 0; j < 8; ++j) {
    v[j] = (float)a0[j] + (float)a1[j] + (float)a2[j] + (float)a3[j];
    ss += v[j] * v[j];
  }
#pragma unroll
  for (int msk = 1; msk < 64; msk <<= 1) ss += __shfl_xor(ss, msk);
  __shared__ float red[4];
  if ((tid & 63) == 0) red[tid >> 6] = ss;
  __syncthreads();
  ss = red[0] + red[1] + red[2] + red[3];
  float sc = 1.0f / fmaxf(sqrtf(ss), 1e-12f);
  float4 oa = { v[0] * sc, v[1] * sc, v[2] * sc, v[3] * sc };
  float4 obv = { v[4] * sc, v[5] * sc, v[6] * sc, v[7] * sc };
  float4* o = (float4*)(out + base);
  o[0] = oa;
  o[1] = obv;
}

extern "C" void kernel_launch(void* const* d_in, const int* in_sizes, int n_in,
                              void* d_out, int out_size, void* d_ws, size_t ws_size,
                              hipStream_t stream) {
  const float* x   = (const float*)d_in[0];
  const float* wq  = (const float*)d_in[1];
  const float* wk  = (const float*)d_in[2];
  const float* wv  = (const float*)d_in[3];
  const float* wo  = (const float*)d_in[4];
  const float* sqk = (const float*)d_in[5];

  float* out_norm = (float*)d_out;
  float* out_k = out_norm + (size_t)4 * 1024 * 1024;
  float* out_v = out_norm + (size_t)8 * 1024 * 1024;

  char* ws = (char*)d_ws;
  unsigned short* xb  = (unsigned short*)(ws);                      // 0..8MB  (dead after QKV)
  unsigned short* w1b = (unsigned short*)(ws + (8u << 20));         // 8..32MB (dead after QKV)
  unsigned short* wob = (unsigned short*)(ws + (32u << 20));        // 32..40MB
  unsigned short* qb  = (unsigned short*)(ws + (40u << 20));        // 40..48MB (dead after attn)
  unsigned short* kb  = (unsigned short*)(ws + (48u << 20));        // 48..56MB (dead after attn)
  unsigned short* vtb = (unsigned short*)(ws + (56u << 20));        // 56..64MB (dead after attn)
  unsigned short* obb = (unsigned short*)(ws + (64u << 20));        // 64..72MB
  unsigned short* qraw = (unsigned short*)(ws + (72u << 20));       // 72..80MB (dead after rope)

  // out-proj split-K=4 bf16 partials (xb/w1b/qb/qraw dead during out-proj)
  unsigned short* Of0 = (unsigned short*)(ws + (72u << 20));  // 72..80MB
  unsigned short* Of1 = (unsigned short*)(ws);                // 0..8MB
  unsigned short* Of2 = (unsigned short*)(ws + (8u << 20));   // 8..16MB
  unsigned short* Of3 = (unsigned short*)(ws + (16u << 20));  // 16..24MB

  // fused converts: one launch, 5 matrices
  k_cvt5<<<dim3(2048, 5), 256, 0, stream>>>(
      x, wq, wk, wv, wo,
      xb, w1b, w1b + (size_t)4 * 1024 * 1024, w1b + (size_t)8 * 1024 * 1024, wob);

  // fused QKV projection (+ fused V-transpose): 2048 x 6144 x 2048, 256 blocks
  k_gemm192<<<dim3(32, 8), 512, 0, stream>>>(xb, w1b, qraw, out_k, out_v, vtb);

  k_rope<<<TT, 256, 0, stream>>>(qraw, out_k, sqk, qb, kb);

  // attention: 4-wave blocks, 512 blocks (2/CU), dispatch-paired causal balance
  k_attn<<<dim3(16, 32), 256, 0, stream>>>(qb, kb, vtb, obb);

  // output projection: 2048 x 2048 x 2048, split-K=4 (256 blocks), bf16 partials
  k_gemm8p<<<dim3(8, 8, 4), 512, 0, stream>>>(obb, wob, CC, CC, CC / 4,
                                              Of0, Of1, Of2, Of3);

  k_l2norm<<<TT, 256, 0, stream>>>(Of0, Of1, Of2, Of3, out_norm);
}